// Round 15
// baseline (86.203 us; speedup 1.0000x reference)
//
#include <hip/hip_runtime.h>
#include <cstdint>
#include <cstddef>

// LSTMCreature, seq_len=1, h0=c0=0:
//   per layer: g = x @ Wih(gate rows).T + (bih+bhh); h = sig(go)*tanh(sig(gi)*tanh(gg))
//   f-gate skipped (multiplies c0=0), W_hh unused (h0=0).
// R15: DE-ROTATED inner loop (kill the spill) + grid-replication diagnostic.
// R12's counters: WRITE 196MB vs 24MB algorithmic => ~57MB/iter scratch writes
// = the 18us/layer invariant. Reg pool ~512/SIMD-slot (m69) => (256,4) caps at
// 128/wave = 64 AGPR acc + 64 arch; the explicit a/w/an/wn rotation (~75 arch
// live) spilled. Fix: direct per-kt loads, live set ~50 arch. Verify: layer 2
// runs grid 3x1024 with bid = blockIdx.x & 1023 (replicas write identical
// bytes to hB) so the dispatch surfaces in rocprof top-5 with true
// VGPR_Count / FETCH / WRITE. Diagnostic removed next round.

#define NROWS 16384
#define HSZ   256

typedef _Float16 half8  __attribute__((ext_vector_type(8)));
typedef _Float16 half4v __attribute__((ext_vector_type(4)));
typedef float    f32x4  __attribute__((ext_vector_type(4)));

__device__ __forceinline__ void gld16(const void* g, void* l) {
    __builtin_amdgcn_global_load_lds(
        (const __attribute__((address_space(1))) void*)g,
        (__attribute__((address_space(3))) void*)l, 16, 0, 0);
}

__device__ __forceinline__ float fsig(float x)  { return 1.f / (1.f + __expf(-x)); }
__device__ __forceinline__ float ftanh(float x) { float e = __expf(2.f * x); return 1.f - 2.f / (e + 1.f); }

__device__ __forceinline__ int gate_remap(int row) {   // 768-row id -> 1024-row src (gates i,g,o)
    int g8 = row >> 8;
    int gate = (g8 == 0) ? 0 : g8 + 1;
    return gate * 256 + (row & 255);
}

// ---------------- fused prep: everything -> frag-linear fp16 ----------------

#define PS0 262144            /* x: 16384*128/8 half8-groups */
#define PS1 (PS0 + 12288)     /* W0: 768*128/8 */
#define PS2 (PS1 + 24576)     /* W1: 768*256/8 */
#define PS3 (PS2 + 24576)     /* W2 */
#define PS4 (PS3 + 2304)      /* bsums */
#define PS5 (PS4 + 4096)      /* fcW: 64*256/4 */

__global__ __launch_bounds__(256)
void prep_all_kernel(const float* __restrict__ x,
                     const float* __restrict__ W0, const float* __restrict__ b0i, const float* __restrict__ b0h,
                     const float* __restrict__ W1, const float* __restrict__ b1i, const float* __restrict__ b1h,
                     const float* __restrict__ W2, const float* __restrict__ b2i, const float* __restrict__ b2h,
                     const float* __restrict__ fcW,
                     _Float16* __restrict__ xf,
                     _Float16* __restrict__ W0f, _Float16* __restrict__ W1f, _Float16* __restrict__ W2f,
                     float* __restrict__ bs0, float* __restrict__ bs1, float* __restrict__ bs2,
                     _Float16* __restrict__ fWh)
{
    const int gid = blockIdx.x * 256 + threadIdx.x;
    if (gid < PS0) {
        int row = gid >> 4, kg = gid & 15;            // kg: 8-elem k-group
        const float* s = x + (size_t)row * 128 + kg * 8;
        f32x4 v0 = *(const f32x4*)s, v1 = *(const f32x4*)(s + 4);
        half8 h;
#pragma unroll
        for (int j = 0; j < 4; ++j) { h[j] = (_Float16)v0[j]; h[4 + j] = (_Float16)v1[j]; }
        int lane = (row & 15) | ((kg & 3) << 4);
        size_t idx = (((size_t)(row >> 4) * 4 + (kg >> 2)) * 64 + lane) * 8;
        *(half8*)(xf + idx) = h;
    } else if (gid < PS3) {
        const float* W; _Float16* Wf; int j, K, r768, kg, NTw;
        if (gid < PS1)      { j = gid - PS0; K = 128; W = W0; Wf = W0f; r768 = j >> 4; kg = j & 15; NTw = 4; }
        else if (gid < PS2) { j = gid - PS1; K = 256; W = W1; Wf = W1f; r768 = j >> 5; kg = j & 31; NTw = 8; }
        else                { j = gid - PS2; K = 256; W = W2; Wf = W2f; r768 = j >> 5; kg = j & 31; NTw = 8; }
        int src = gate_remap(r768);
        const float* s = W + (size_t)src * K + kg * 8;
        f32x4 v0 = *(const f32x4*)s, v1 = *(const f32x4*)(s + 4);
        half8 h;
#pragma unroll
        for (int jj = 0; jj < 4; ++jj) { h[jj] = (_Float16)v0[jj]; h[4 + jj] = (_Float16)v1[jj]; }
        int lane = (r768 & 15) | ((kg & 3) << 4);
        size_t idx = (((size_t)(r768 >> 4) * NTw + (kg >> 2)) * 64 + lane) * 8;
        *(half8*)(Wf + idx) = h;
    } else if (gid < PS4) {
        int j = gid - PS3;
        int l = (j >= 1536) ? 2 : (j >= 768 ? 1 : 0);
        int r = j - l * 768;
        int src = gate_remap(r);
        const float* bi = (l == 0) ? b0i : (l == 1) ? b1i : b2i;
        const float* bh = (l == 0) ? b0h : (l == 1) ? b1h : b2h;
        float* bs       = (l == 0) ? bs0 : (l == 1) ? bs1 : bs2;
        bs[r] = bi[src] + bh[src];
    } else if (gid < PS5) {
        int j = gid - PS4;            // 0..4095: fcW 64x256 in f32x4 chunks (LINEAR)
        f32x4 v = ((const f32x4*)fcW)[j];
        half4v h;
#pragma unroll
        for (int jj = 0; jj < 4; ++jj) h[jj] = (_Float16)v[jj];
        ((half4v*)fWh)[j] = h;
    }
}

// ---------------- layer kernel: 4 waves/block, frag-linear, de-rotated ----------------
// blockIdx & 1023 -> bid (grid may be a multiple of 1024: replicas compute and
// write IDENTICAL bytes -> benign; used as a timing diagnostic).
// bid -> xc=bid&7, q=bid>>3 (0..127): M = xc + 8*(q>>2), nu = (q&3)*4 + wave.
// Per k-tile: 4 A frags + 3 W frags loaded DIRECTLY (static offsets) + 12 MFMA.
// Live set ~50 arch + 64 acc fits the 128/wave budget of (256,4): no spill.

template<int K>
__global__ __launch_bounds__(256, 4)
void lstm_mfma_kernel(const _Float16* __restrict__ Af,   // frag-linear [ru][NT][64][8]
                      const _Float16* __restrict__ Wf,   // frag-linear [48][NT][64][8]
                      const float* __restrict__ bsum,    // [768] linear
                      _Float16* __restrict__ Of)         // frag-linear [ru][8][64][8]
{
    constexpr int NT = K / 32;
    const int t    = threadIdx.x;
    const int lane = t & 63;
    const int wave = t >> 6;
    const int lrow = lane & 15;
    const int lkb  = lane >> 4;

    const int bid = blockIdx.x & 1023;
    const int xc  = bid & 7, q = bid >> 3;
    const int nu  = (q & 3) * 4 + wave;
    const int M   = xc + ((q >> 2) << 3);

    const _Float16* pA = Af + ((size_t)(M * 4) * NT) * 512 + lane * 8;
    const _Float16* pW = Wf + ((size_t)nu * NT) * 512 + lane * 8;
    // A frag (fm, kt) at pA + (fm*NT + kt)*512 ; W frag (g, kt) at pW + (g*16*NT + kt)*512

    f32x4 acc[3][4];
#pragma unroll
    for (int g = 0; g < 3; ++g)
#pragma unroll
        for (int fm = 0; fm < 4; ++fm) acc[g][fm] = (f32x4)0.f;

#pragma unroll
    for (int kt = 0; kt < NT; ++kt) {
        half8 a0 = *(const half8*)(pA + (size_t)(0 * NT + kt) * 512);
        half8 a1 = *(const half8*)(pA + (size_t)(1 * NT + kt) * 512);
        half8 a2 = *(const half8*)(pA + (size_t)(2 * NT + kt) * 512);
        half8 a3 = *(const half8*)(pA + (size_t)(3 * NT + kt) * 512);
        half8 w0 = *(const half8*)(pW + (size_t)(0 * 16 * NT + kt) * 512);
        half8 w1 = *(const half8*)(pW + (size_t)(16 * NT + kt) * 512);
        half8 w2 = *(const half8*)(pW + (size_t)(32 * NT + kt) * 512);
        acc[0][0] = __builtin_amdgcn_mfma_f32_16x16x32_f16(w0, a0, acc[0][0], 0, 0, 0);
        acc[0][1] = __builtin_amdgcn_mfma_f32_16x16x32_f16(w0, a1, acc[0][1], 0, 0, 0);
        acc[0][2] = __builtin_amdgcn_mfma_f32_16x16x32_f16(w0, a2, acc[0][2], 0, 0, 0);
        acc[0][3] = __builtin_amdgcn_mfma_f32_16x16x32_f16(w0, a3, acc[0][3], 0, 0, 0);
        acc[1][0] = __builtin_amdgcn_mfma_f32_16x16x32_f16(w1, a0, acc[1][0], 0, 0, 0);
        acc[1][1] = __builtin_amdgcn_mfma_f32_16x16x32_f16(w1, a1, acc[1][1], 0, 0, 0);
        acc[1][2] = __builtin_amdgcn_mfma_f32_16x16x32_f16(w1, a2, acc[1][2], 0, 0, 0);
        acc[1][3] = __builtin_amdgcn_mfma_f32_16x16x32_f16(w1, a3, acc[1][3], 0, 0, 0);
        acc[2][0] = __builtin_amdgcn_mfma_f32_16x16x32_f16(w2, a0, acc[2][0], 0, 0, 0);
        acc[2][1] = __builtin_amdgcn_mfma_f32_16x16x32_f16(w2, a1, acc[2][1], 0, 0, 0);
        acc[2][2] = __builtin_amdgcn_mfma_f32_16x16x32_f16(w2, a2, acc[2][2], 0, 0, 0);
        acc[2][3] = __builtin_amdgcn_mfma_f32_16x16x32_f16(w2, a3, acc[2][3], 0, 0, 0);
    }

    // epilogue: n = nu*16 + lkb*4 + j ; m = M*64 + fm*16 + lrow.
    // Frag-linear store for NT=8 consumer:
    //   kt_o = nu>>1 ; lane_o = lrow | (((nu&1)<<1 | (lkb>>1))<<4) ; elem = (lkb&1)*4
    const int nbase = nu * 16 + lkb * 4;
    const f32x4 bI = *(const f32x4*)(bsum + nbase);
    const f32x4 bG = *(const f32x4*)(bsum + 256 + nbase);
    const f32x4 bO = *(const f32x4*)(bsum + 512 + nbase);

    const int kt_o   = nu >> 1;
    const int lane_o = lrow | ((((nu & 1) << 1) | (lkb >> 1)) << 4);
    const int elem   = (lkb & 1) * 4;

#pragma unroll
    for (int fm = 0; fm < 4; ++fm) {
        half4v oh;
#pragma unroll
        for (int j = 0; j < 4; ++j) {
            float gi = acc[0][fm][j] + bI[j];
            float gg = acc[1][fm][j] + bG[j];
            float go = acc[2][fm][j] + bO[j];
            float c2 = fsig(gi) * ftanh(gg);
            oh[j] = (_Float16)(fsig(go) * ftanh(c2));
        }
        size_t idx = (((size_t)(M * 4 + fm) * 8 + kt_o) * 64 + lane_o) * 8 + elem;
        *(half4v*)(Of + idx) = oh;
    }
}

// ---------------- FC (MFMA, frag-linear H reads) + fused tanh-softmax-normalize ----------------

__global__ __launch_bounds__(256)
void fc_softmax_kernel(const _Float16* __restrict__ Hf,
                       const _Float16* __restrict__ fWh,
                       const float* __restrict__ fcb, float* __restrict__ out)
{
    __shared__ __align__(16) _Float16 sWh[64 * 256];   // 32KB

    const int t    = threadIdx.x;
    const int lane = t & 63;
    const int wave = t >> 6;
    const int ln   = lane & 15;
    const int lkb  = lane >> 4;
    const int m0   = blockIdx.x * 64;
    const int ru   = blockIdx.x * 4 + wave;

    // stage fcW plane via gld16: linear dest + inverse-swizzled source
#pragma unroll
    for (int i = 0; i < 8; ++i) {
        int j = i * 256 + t;            // 0..2047
        int row = j >> 5, c = j & 31;
        int cs  = c ^ (row & 7);
        gld16(fWh + row * 256 + cs * 8, sWh + j * 8);
    }

    const _Float16* pH = Hf + ((size_t)ru * 8) * 512 + lane * 8;

    f32x4 acc[4];
#pragma unroll
    for (int nf = 0; nf < 4; ++nf) acc[nf] = (f32x4)0.f;

    __syncthreads();   // drains gld16 (vmcnt 0) + orders LDS

#pragma unroll
    for (int kt = 0; kt < 8; ++kt) {
        half8 ah = *(const half8*)(pH + (size_t)kt * 512);
        __builtin_amdgcn_s_setprio(1);
#pragma unroll
        for (int nf = 0; nf < 4; ++nf) {
            int wr  = nf * 16 + ln;
            int ch  = kt * 4 + lkb;
            int off = wr * 256 + ((ch ^ (wr & 7)) << 3);
            half8 wwh = *(const half8*)(&sWh[off]);
            acc[nf] = __builtin_amdgcn_mfma_f32_16x16x32_f16(ah, wwh, acc[nf], 0, 0, 0);
        }
        __builtin_amdgcn_s_setprio(0);
    }

    // ---- epilogue: bias + tanh-softmax-normalize over n (64) per row ----
    float fb[4];
#pragma unroll
    for (int nf = 0; nf < 4; ++nf) fb[nf] = fcb[nf * 16 + ln];

    float tt[4][4], aa[4][4];
#pragma unroll
    for (int nf = 0; nf < 4; ++nf)
#pragma unroll
        for (int r = 0; r < 4; ++r) {
            float o = acc[nf][r] + fb[nf];
            tt[nf][r] = ftanh(o);
            aa[nf][r] = fabsf(o);
        }

    float mx[4];
#pragma unroll
    for (int r = 0; r < 4; ++r)
        mx[r] = fmaxf(fmaxf(aa[0][r], aa[1][r]), fmaxf(aa[2][r], aa[3][r]));
#pragma unroll
    for (int ofs = 1; ofs < 16; ofs <<= 1)
#pragma unroll
        for (int r = 0; r < 4; ++r) mx[r] = fmaxf(mx[r], __shfl_xor(mx[r], ofs, 64));

    float ee[4][4], Z[4];
#pragma unroll
    for (int r = 0; r < 4; ++r) Z[r] = 0.f;
#pragma unroll
    for (int nf = 0; nf < 4; ++nf)
#pragma unroll
        for (int r = 0; r < 4; ++r) { ee[nf][r] = __expf(aa[nf][r] - mx[r]); Z[r] += ee[nf][r]; }
#pragma unroll
    for (int ofs = 1; ofs < 16; ofs <<= 1)
#pragma unroll
        for (int r = 0; r < 4; ++r) Z[r] += __shfl_xor(Z[r], ofs, 64);

    float w[4][4], S[4];
#pragma unroll
    for (int r = 0; r < 4; ++r) S[r] = 0.f;
#pragma unroll
    for (int nf = 0; nf < 4; ++nf)
#pragma unroll
        for (int r = 0; r < 4; ++r) { w[nf][r] = tt[nf][r] * ee[nf][r] / Z[r]; S[r] += fabsf(w[nf][r]); }
#pragma unroll
    for (int ofs = 1; ofs < 16; ofs <<= 1)
#pragma unroll
        for (int r = 0; r < 4; ++r) S[r] += __shfl_xor(S[r], ofs, 64);

#pragma unroll
    for (int r = 0; r < 4; ++r) {
        const float inv = 1.f / fmaxf(S[r], 1e-12f);
        const int m = m0 + wave * 16 + lkb * 4 + r;
#pragma unroll
        for (int nf = 0; nf < 4; ++nf)
            out[(size_t)m * 64 + nf * 16 + ln] = w[nf][r] * inv;
    }
}

// ---------------- launch ----------------

extern "C" void kernel_launch(void* const* d_in, const int* in_sizes, int n_in,
                              void* d_out, int out_size, void* d_ws, size_t ws_size,
                              hipStream_t stream) {
    const float* x    = (const float*)d_in[0];
    const float* Wih0 = (const float*)d_in[1];
    const float* bih0 = (const float*)d_in[3];
    const float* bhh0 = (const float*)d_in[4];
    const float* Wih1 = (const float*)d_in[5];
    const float* bih1 = (const float*)d_in[7];
    const float* bhh1 = (const float*)d_in[8];
    const float* Wih2 = (const float*)d_in[9];
    const float* bih2 = (const float*)d_in[11];
    const float* bhh2 = (const float*)d_in[12];
    const float* fcW  = (const float*)d_in[13];
    const float* fcb  = (const float*)d_in[14];

    char* ws = (char*)d_ws;
    _Float16* hA  = (_Float16*)(ws);                   // 8 MB frag-linear
    _Float16* hB  = (_Float16*)(ws + (8u  << 20));     // 8 MB frag-linear
    _Float16* xf  = (_Float16*)(ws + (16u << 20));     // 4 MB frag-linear
    _Float16* W0f = (_Float16*)(ws + (20u << 20));     // 192 KB
    _Float16* W1f = (_Float16*)(ws + (21u << 20));     // 384 KB
    _Float16* W2f = (_Float16*)(ws + (22u << 20));     // 384 KB
    _Float16* fWh = (_Float16*)(ws + (23u << 20));     // 32 KB linear
    float*    bs0 = (float*)(ws + (24u << 20));
    float*    bs1 = (float*)(ws + (24u << 20) + 4096);
    float*    bs2 = (float*)(ws + (24u << 20) + 8192);
    float*    outp = (float*)d_out;

    prep_all_kernel<<<dim3(PS5 / 256), dim3(256), 0, stream>>>(
        x, Wih0, bih0, bhh0, Wih1, bih1, bhh1, Wih2, bih2, bhh2, fcW,
        xf, W0f, W1f, W2f, bs0, bs1, bs2, fWh);

    lstm_mfma_kernel<128><<<dim3(1024), dim3(256), 0, stream>>>(xf, W0f, bs0, hA);
    // DIAGNOSTIC: 3x grid; replicas (blockIdx>=1024) write identical bytes to hB.
    lstm_mfma_kernel<256><<<dim3(3072), dim3(256), 0, stream>>>(hA, W1f, bs1, hB);
    lstm_mfma_kernel<256><<<dim3(1024), dim3(256), 0, stream>>>(hB, W2f, bs2, hA);

    fc_softmax_kernel<<<dim3(256), dim3(256), 0, stream>>>(hA, fWh, fcb, outp);
}

// Round 16
// 51.721 us; speedup vs baseline: 1.6667x; 1.6667x over previous
//
#include <hip/hip_runtime.h>
#include <cstdint>
#include <cstddef>

// LSTMCreature, seq_len=1, h0=c0=0:
//   per layer: g = x @ Wih(gate rows).T + (bih+bhh); h = sig(go)*tanh(sig(gi)*tanh(gg))
//   f-gate skipped (multiplies c0=0), W_hh unused (h0=0).
// R16: FAST-RCP EPILOGUE. R15's surfaced counters: MfmaUtil 15.5% (MFMA ~2.4us
// = ideal), VALUBusy 52% = 3.4x MFMA cycles, FETCH 5.7MB (memory exonerated).
// Cause: epilogue 1.f/x divisions compile to ~10-inst correctly-rounded div
// sequences (no fast-math) -> ~55 VALU/elem x 4.2M elems ~ 7-8us/layer = the
// session-long invariant. Fix: v_rcp_f32 (__builtin_amdgcn_rcpf, 1-ulp f32,
// error 1e-7 << fp16 h-quantization). Everything else = R15 (de-rotated
// frag-linear dataflow, 4-wave blocks, (256,4), XCD-local swizzle).

#define NROWS 16384
#define HSZ   256

typedef _Float16 half8  __attribute__((ext_vector_type(8)));
typedef _Float16 half4v __attribute__((ext_vector_type(4)));
typedef float    f32x4  __attribute__((ext_vector_type(4)));

__device__ __forceinline__ void gld16(const void* g, void* l) {
    __builtin_amdgcn_global_load_lds(
        (const __attribute__((address_space(1))) void*)g,
        (__attribute__((address_space(3))) void*)l, 16, 0, 0);
}

__device__ __forceinline__ float frcp(float x)  { return __builtin_amdgcn_rcpf(x); }
__device__ __forceinline__ float fsig(float x)  { return frcp(1.f + __expf(-x)); }
__device__ __forceinline__ float ftanh(float x) { return 1.f - 2.f * frcp(__expf(2.f * x) + 1.f); }

__device__ __forceinline__ int gate_remap(int row) {   // 768-row id -> 1024-row src (gates i,g,o)
    int g8 = row >> 8;
    int gate = (g8 == 0) ? 0 : g8 + 1;
    return gate * 256 + (row & 255);
}

// ---------------- fused prep: everything -> frag-linear fp16 ----------------

#define PS0 262144            /* x: 16384*128/8 half8-groups */
#define PS1 (PS0 + 12288)     /* W0: 768*128/8 */
#define PS2 (PS1 + 24576)     /* W1: 768*256/8 */
#define PS3 (PS2 + 24576)     /* W2 */
#define PS4 (PS3 + 2304)      /* bsums */
#define PS5 (PS4 + 4096)      /* fcW: 64*256/4 */

__global__ __launch_bounds__(256)
void prep_all_kernel(const float* __restrict__ x,
                     const float* __restrict__ W0, const float* __restrict__ b0i, const float* __restrict__ b0h,
                     const float* __restrict__ W1, const float* __restrict__ b1i, const float* __restrict__ b1h,
                     const float* __restrict__ W2, const float* __restrict__ b2i, const float* __restrict__ b2h,
                     const float* __restrict__ fcW,
                     _Float16* __restrict__ xf,
                     _Float16* __restrict__ W0f, _Float16* __restrict__ W1f, _Float16* __restrict__ W2f,
                     float* __restrict__ bs0, float* __restrict__ bs1, float* __restrict__ bs2,
                     _Float16* __restrict__ fWh)
{
    const int gid = blockIdx.x * 256 + threadIdx.x;
    if (gid < PS0) {
        int row = gid >> 4, kg = gid & 15;            // kg: 8-elem k-group
        const float* s = x + (size_t)row * 128 + kg * 8;
        f32x4 v0 = *(const f32x4*)s, v1 = *(const f32x4*)(s + 4);
        half8 h;
#pragma unroll
        for (int j = 0; j < 4; ++j) { h[j] = (_Float16)v0[j]; h[4 + j] = (_Float16)v1[j]; }
        int lane = (row & 15) | ((kg & 3) << 4);
        size_t idx = (((size_t)(row >> 4) * 4 + (kg >> 2)) * 64 + lane) * 8;
        *(half8*)(xf + idx) = h;
    } else if (gid < PS3) {
        const float* W; _Float16* Wf; int j, K, r768, kg, NTw;
        if (gid < PS1)      { j = gid - PS0; K = 128; W = W0; Wf = W0f; r768 = j >> 4; kg = j & 15; NTw = 4; }
        else if (gid < PS2) { j = gid - PS1; K = 256; W = W1; Wf = W1f; r768 = j >> 5; kg = j & 31; NTw = 8; }
        else                { j = gid - PS2; K = 256; W = W2; Wf = W2f; r768 = j >> 5; kg = j & 31; NTw = 8; }
        int src = gate_remap(r768);
        const float* s = W + (size_t)src * K + kg * 8;
        f32x4 v0 = *(const f32x4*)s, v1 = *(const f32x4*)(s + 4);
        half8 h;
#pragma unroll
        for (int jj = 0; jj < 4; ++jj) { h[jj] = (_Float16)v0[jj]; h[4 + jj] = (_Float16)v1[jj]; }
        int lane = (r768 & 15) | ((kg & 3) << 4);
        size_t idx = (((size_t)(r768 >> 4) * NTw + (kg >> 2)) * 64 + lane) * 8;
        *(half8*)(Wf + idx) = h;
    } else if (gid < PS4) {
        int j = gid - PS3;
        int l = (j >= 1536) ? 2 : (j >= 768 ? 1 : 0);
        int r = j - l * 768;
        int src = gate_remap(r);
        const float* bi = (l == 0) ? b0i : (l == 1) ? b1i : b2i;
        const float* bh = (l == 0) ? b0h : (l == 1) ? b1h : b2h;
        float* bs       = (l == 0) ? bs0 : (l == 1) ? bs1 : bs2;
        bs[r] = bi[src] + bh[src];
    } else if (gid < PS5) {
        int j = gid - PS4;            // 0..4095: fcW 64x256 in f32x4 chunks (LINEAR)
        f32x4 v = ((const f32x4*)fcW)[j];
        half4v h;
#pragma unroll
        for (int jj = 0; jj < 4; ++jj) h[jj] = (_Float16)v[jj];
        ((half4v*)fWh)[j] = h;
    }
}

// ---------------- layer kernel: 4 waves/block, frag-linear, de-rotated ----------------
// bid -> xc=bid&7, q=bid>>3 (0..127): M = xc + 8*(q>>2), nu = (q&3)*4 + wave.
// Per k-tile: 4 A frags + 3 W frags loaded DIRECTLY (static offsets) + 12 MFMA.
// VGPR 56 arch + 64 acc fits (256,4): no spill (verified R15: WRITE = algorithmic).

template<int K>
__global__ __launch_bounds__(256, 4)
void lstm_mfma_kernel(const _Float16* __restrict__ Af,   // frag-linear [ru][NT][64][8]
                      const _Float16* __restrict__ Wf,   // frag-linear [48][NT][64][8]
                      const float* __restrict__ bsum,    // [768] linear
                      _Float16* __restrict__ Of)         // frag-linear [ru][8][64][8]
{
    constexpr int NT = K / 32;
    const int t    = threadIdx.x;
    const int lane = t & 63;
    const int wave = t >> 6;
    const int lrow = lane & 15;
    const int lkb  = lane >> 4;

    const int bid = blockIdx.x;
    const int xc  = bid & 7, q = bid >> 3;
    const int nu  = (q & 3) * 4 + wave;
    const int M   = xc + ((q >> 2) << 3);

    const _Float16* pA = Af + ((size_t)(M * 4) * NT) * 512 + lane * 8;
    const _Float16* pW = Wf + ((size_t)nu * NT) * 512 + lane * 8;
    // A frag (fm, kt) at pA + (fm*NT + kt)*512 ; W frag (g, kt) at pW + (g*16*NT + kt)*512

    f32x4 acc[3][4];
#pragma unroll
    for (int g = 0; g < 3; ++g)
#pragma unroll
        for (int fm = 0; fm < 4; ++fm) acc[g][fm] = (f32x4)0.f;

#pragma unroll
    for (int kt = 0; kt < NT; ++kt) {
        half8 a0 = *(const half8*)(pA + (size_t)(0 * NT + kt) * 512);
        half8 a1 = *(const half8*)(pA + (size_t)(1 * NT + kt) * 512);
        half8 a2 = *(const half8*)(pA + (size_t)(2 * NT + kt) * 512);
        half8 a3 = *(const half8*)(pA + (size_t)(3 * NT + kt) * 512);
        half8 w0 = *(const half8*)(pW + (size_t)(0 * 16 * NT + kt) * 512);
        half8 w1 = *(const half8*)(pW + (size_t)(16 * NT + kt) * 512);
        half8 w2 = *(const half8*)(pW + (size_t)(32 * NT + kt) * 512);
        acc[0][0] = __builtin_amdgcn_mfma_f32_16x16x32_f16(w0, a0, acc[0][0], 0, 0, 0);
        acc[0][1] = __builtin_amdgcn_mfma_f32_16x16x32_f16(w0, a1, acc[0][1], 0, 0, 0);
        acc[0][2] = __builtin_amdgcn_mfma_f32_16x16x32_f16(w0, a2, acc[0][2], 0, 0, 0);
        acc[0][3] = __builtin_amdgcn_mfma_f32_16x16x32_f16(w0, a3, acc[0][3], 0, 0, 0);
        acc[1][0] = __builtin_amdgcn_mfma_f32_16x16x32_f16(w1, a0, acc[1][0], 0, 0, 0);
        acc[1][1] = __builtin_amdgcn_mfma_f32_16x16x32_f16(w1, a1, acc[1][1], 0, 0, 0);
        acc[1][2] = __builtin_amdgcn_mfma_f32_16x16x32_f16(w1, a2, acc[1][2], 0, 0, 0);
        acc[1][3] = __builtin_amdgcn_mfma_f32_16x16x32_f16(w1, a3, acc[1][3], 0, 0, 0);
        acc[2][0] = __builtin_amdgcn_mfma_f32_16x16x32_f16(w2, a0, acc[2][0], 0, 0, 0);
        acc[2][1] = __builtin_amdgcn_mfma_f32_16x16x32_f16(w2, a1, acc[2][1], 0, 0, 0);
        acc[2][2] = __builtin_amdgcn_mfma_f32_16x16x32_f16(w2, a2, acc[2][2], 0, 0, 0);
        acc[2][3] = __builtin_amdgcn_mfma_f32_16x16x32_f16(w2, a3, acc[2][3], 0, 0, 0);
    }

    // epilogue: n = nu*16 + lkb*4 + j ; m = M*64 + fm*16 + lrow.
    // Frag-linear store for NT=8 consumer:
    //   kt_o = nu>>1 ; lane_o = lrow | (((nu&1)<<1 | (lkb>>1))<<4) ; elem = (lkb&1)*4
    const int nbase = nu * 16 + lkb * 4;
    const f32x4 bI = *(const f32x4*)(bsum + nbase);
    const f32x4 bG = *(const f32x4*)(bsum + 256 + nbase);
    const f32x4 bO = *(const f32x4*)(bsum + 512 + nbase);

    const int kt_o   = nu >> 1;
    const int lane_o = lrow | ((((nu & 1) << 1) | (lkb >> 1)) << 4);
    const int elem   = (lkb & 1) * 4;

#pragma unroll
    for (int fm = 0; fm < 4; ++fm) {
        half4v oh;
#pragma unroll
        for (int j = 0; j < 4; ++j) {
            float gi = acc[0][fm][j] + bI[j];
            float gg = acc[1][fm][j] + bG[j];
            float go = acc[2][fm][j] + bO[j];
            float c2 = fsig(gi) * ftanh(gg);
            oh[j] = (_Float16)(fsig(go) * ftanh(c2));
        }
        size_t idx = (((size_t)(M * 4 + fm) * 8 + kt_o) * 64 + lane_o) * 8 + elem;
        *(half4v*)(Of + idx) = oh;
    }
}

// ---------------- FC (MFMA, frag-linear H reads) + fused tanh-softmax-normalize ----------------

__global__ __launch_bounds__(256)
void fc_softmax_kernel(const _Float16* __restrict__ Hf,
                       const _Float16* __restrict__ fWh,
                       const float* __restrict__ fcb, float* __restrict__ out)
{
    __shared__ __align__(16) _Float16 sWh[64 * 256];   // 32KB

    const int t    = threadIdx.x;
    const int lane = t & 63;
    const int wave = t >> 6;
    const int ln   = lane & 15;
    const int lkb  = lane >> 4;
    const int m0   = blockIdx.x * 64;
    const int ru   = blockIdx.x * 4 + wave;

    // stage fcW plane via gld16: linear dest + inverse-swizzled source
#pragma unroll
    for (int i = 0; i < 8; ++i) {
        int j = i * 256 + t;            // 0..2047
        int row = j >> 5, c = j & 31;
        int cs  = c ^ (row & 7);
        gld16(fWh + row * 256 + cs * 8, sWh + j * 8);
    }

    const _Float16* pH = Hf + ((size_t)ru * 8) * 512 + lane * 8;

    f32x4 acc[4];
#pragma unroll
    for (int nf = 0; nf < 4; ++nf) acc[nf] = (f32x4)0.f;

    __syncthreads();   // drains gld16 (vmcnt 0) + orders LDS

#pragma unroll
    for (int kt = 0; kt < 8; ++kt) {
        half8 ah = *(const half8*)(pH + (size_t)kt * 512);
        __builtin_amdgcn_s_setprio(1);
#pragma unroll
        for (int nf = 0; nf < 4; ++nf) {
            int wr  = nf * 16 + ln;
            int ch  = kt * 4 + lkb;
            int off = wr * 256 + ((ch ^ (wr & 7)) << 3);
            half8 wwh = *(const half8*)(&sWh[off]);
            acc[nf] = __builtin_amdgcn_mfma_f32_16x16x32_f16(ah, wwh, acc[nf], 0, 0, 0);
        }
        __builtin_amdgcn_s_setprio(0);
    }

    // ---- epilogue: bias + tanh-softmax-normalize over n (64) per row ----
    float fb[4];
#pragma unroll
    for (int nf = 0; nf < 4; ++nf) fb[nf] = fcb[nf * 16 + ln];

    float tt[4][4], aa[4][4];
#pragma unroll
    for (int nf = 0; nf < 4; ++nf)
#pragma unroll
        for (int r = 0; r < 4; ++r) {
            float o = acc[nf][r] + fb[nf];
            tt[nf][r] = ftanh(o);
            aa[nf][r] = fabsf(o);
        }

    float mx[4];
#pragma unroll
    for (int r = 0; r < 4; ++r)
        mx[r] = fmaxf(fmaxf(aa[0][r], aa[1][r]), fmaxf(aa[2][r], aa[3][r]));
#pragma unroll
    for (int ofs = 1; ofs < 16; ofs <<= 1)
#pragma unroll
        for (int r = 0; r < 4; ++r) mx[r] = fmaxf(mx[r], __shfl_xor(mx[r], ofs, 64));

    float ee[4][4], Z[4];
#pragma unroll
    for (int r = 0; r < 4; ++r) Z[r] = 0.f;
#pragma unroll
    for (int nf = 0; nf < 4; ++nf)
#pragma unroll
        for (int r = 0; r < 4; ++r) { ee[nf][r] = __expf(aa[nf][r] - mx[r]); Z[r] += ee[nf][r]; }
#pragma unroll
    for (int ofs = 1; ofs < 16; ofs <<= 1)
#pragma unroll
        for (int r = 0; r < 4; ++r) Z[r] += __shfl_xor(Z[r], ofs, 64);

    float w[4][4], S[4];
#pragma unroll
    for (int r = 0; r < 4; ++r) S[r] = 0.f;
#pragma unroll
    for (int r = 0; r < 4; ++r) {
        const float rz = __builtin_amdgcn_rcpf(Z[r]);
#pragma unroll
        for (int nf = 0; nf < 4; ++nf) { w[nf][r] = tt[nf][r] * ee[nf][r] * rz; S[r] += fabsf(w[nf][r]); }
    }
#pragma unroll
    for (int ofs = 1; ofs < 16; ofs <<= 1)
#pragma unroll
        for (int r = 0; r < 4; ++r) S[r] += __shfl_xor(S[r], ofs, 64);

#pragma unroll
    for (int r = 0; r < 4; ++r) {
        const float inv = __builtin_amdgcn_rcpf(fmaxf(S[r], 1e-12f));
        const int m = m0 + wave * 16 + lkb * 4 + r;
#pragma unroll
        for (int nf = 0; nf < 4; ++nf)
            out[(size_t)m * 64 + nf * 16 + ln] = w[nf][r] * inv;
    }
}

// ---------------- launch ----------------

extern "C" void kernel_launch(void* const* d_in, const int* in_sizes, int n_in,
                              void* d_out, int out_size, void* d_ws, size_t ws_size,
                              hipStream_t stream) {
    const float* x    = (const float*)d_in[0];
    const float* Wih0 = (const float*)d_in[1];
    const float* bih0 = (const float*)d_in[3];
    const float* bhh0 = (const float*)d_in[4];
    const float* Wih1 = (const float*)d_in[5];
    const float* bih1 = (const float*)d_in[7];
    const float* bhh1 = (const float*)d_in[8];
    const float* Wih2 = (const float*)d_in[9];
    const float* bih2 = (const float*)d_in[11];
    const float* bhh2 = (const float*)d_in[12];
    const float* fcW  = (const float*)d_in[13];
    const float* fcb  = (const float*)d_in[14];

    char* ws = (char*)d_ws;
    _Float16* hA  = (_Float16*)(ws);                   // 8 MB frag-linear
    _Float16* hB  = (_Float16*)(ws + (8u  << 20));     // 8 MB frag-linear
    _Float16* xf  = (_Float16*)(ws + (16u << 20));     // 4 MB frag-linear
    _Float16* W0f = (_Float16*)(ws + (20u << 20));     // 192 KB
    _Float16* W1f = (_Float16*)(ws + (21u << 20));     // 384 KB
    _Float16* W2f = (_Float16*)(ws + (22u << 20));     // 384 KB
    _Float16* fWh = (_Float16*)(ws + (23u << 20));     // 32 KB linear
    float*    bs0 = (float*)(ws + (24u << 20));
    float*    bs1 = (float*)(ws + (24u << 20) + 4096);
    float*    bs2 = (float*)(ws + (24u << 20) + 8192);
    float*    outp = (float*)d_out;

    prep_all_kernel<<<dim3(PS5 / 256), dim3(256), 0, stream>>>(
        x, Wih0, bih0, bhh0, Wih1, bih1, bhh1, Wih2, bih2, bhh2, fcW,
        xf, W0f, W1f, W2f, bs0, bs1, bs2, fWh);

    lstm_mfma_kernel<128><<<dim3(1024), dim3(256), 0, stream>>>(xf, W0f, bs0, hA);
    lstm_mfma_kernel<256><<<dim3(1024), dim3(256), 0, stream>>>(hA, W1f, bs1, hB);
    lstm_mfma_kernel<256><<<dim3(1024), dim3(256), 0, stream>>>(hB, W2f, bs2, hA);

    fc_softmax_kernel<<<dim3(256), dim3(256), 0, stream>>>(hA, fWh, fcb, outp);
}

// Round 17
// 42.364 us; speedup vs baseline: 2.0348x; 1.2209x over previous
//
#include <hip/hip_runtime.h>
#include <cstdint>
#include <cstddef>

// LSTMCreature, seq_len=1, h0=c0=0:
//   per layer: g = x @ Wih(gate rows).T + (bih+bhh); h = sig(go)*tanh(sig(gi)*tanh(gg))
//   f-gate skipped (multiplies c0=0), W_hh unused (h0=0).
// R17: FULL FUSION. Frag-linear row-block locality => block b (16 waves, wave
// = n-unit) owns rows b*64..b*64+63 through ALL 3 layers + fc with only
// __syncthreads: h1/h2/h3 ping-pong in LDS (2x32KB, same frag formula as the
// verified global path, base swapped). 5 dispatches -> 2; global h traffic
// (24MB writes + 128MB re-reads) -> 0. W per-wave from L2 (no intra-block
// redundancy). rcp-epilogue (R16). (1024,4) = R16's proven 128-reg budget.

#define NROWS 16384
#define HSZ   256

typedef _Float16 half8  __attribute__((ext_vector_type(8)));
typedef _Float16 half4v __attribute__((ext_vector_type(4)));
typedef float    f32x4  __attribute__((ext_vector_type(4)));

__device__ __forceinline__ float frcp(float x)  { return __builtin_amdgcn_rcpf(x); }
__device__ __forceinline__ float fsig(float x)  { return frcp(1.f + __expf(-x)); }
__device__ __forceinline__ float ftanh(float x) { return 1.f - 2.f * frcp(__expf(2.f * x) + 1.f); }

__device__ __forceinline__ int gate_remap(int row) {   // 768-row id -> 1024-row src (gates i,g,o)
    int g8 = row >> 8;
    int gate = (g8 == 0) ? 0 : g8 + 1;
    return gate * 256 + (row & 255);
}

// ---------------- fused prep: everything -> frag-linear fp16 ----------------
// frag layout: elem (row,k) -> ((ru*NT+kt)*64 + lane)*8 + (k&7),
// lane = (row&15) | (((k>>3)&3)<<4), ru = row>>4, kt = k>>5.

#define PS0 262144            /* x: 16384*128/8 half8-groups */
#define PS1 (PS0 + 12288)     /* W0: 768*128/8 */
#define PS2 (PS1 + 24576)     /* W1: 768*256/8 */
#define PS3 (PS2 + 24576)     /* W2 */
#define PS4 (PS3 + 2304)      /* bsums */
#define PS5 (PS4 + 2048)      /* fcW: 64*256/8 frag-linear */

__global__ __launch_bounds__(256)
void prep_all_kernel(const float* __restrict__ x,
                     const float* __restrict__ W0, const float* __restrict__ b0i, const float* __restrict__ b0h,
                     const float* __restrict__ W1, const float* __restrict__ b1i, const float* __restrict__ b1h,
                     const float* __restrict__ W2, const float* __restrict__ b2i, const float* __restrict__ b2h,
                     const float* __restrict__ fcW,
                     _Float16* __restrict__ xf,
                     _Float16* __restrict__ W0f, _Float16* __restrict__ W1f, _Float16* __restrict__ W2f,
                     float* __restrict__ bs0, float* __restrict__ bs1, float* __restrict__ bs2,
                     _Float16* __restrict__ fWf)
{
    const int gid = blockIdx.x * 256 + threadIdx.x;
    if (gid < PS0) {
        int row = gid >> 4, kg = gid & 15;            // kg: 8-elem k-group
        const float* s = x + (size_t)row * 128 + kg * 8;
        f32x4 v0 = *(const f32x4*)s, v1 = *(const f32x4*)(s + 4);
        half8 h;
#pragma unroll
        for (int j = 0; j < 4; ++j) { h[j] = (_Float16)v0[j]; h[4 + j] = (_Float16)v1[j]; }
        int lane = (row & 15) | ((kg & 3) << 4);
        size_t idx = (((size_t)(row >> 4) * 4 + (kg >> 2)) * 64 + lane) * 8;
        *(half8*)(xf + idx) = h;
    } else if (gid < PS3) {
        const float* W; _Float16* Wf; int j, K, r768, kg, NTw;
        if (gid < PS1)      { j = gid - PS0; K = 128; W = W0; Wf = W0f; r768 = j >> 4; kg = j & 15; NTw = 4; }
        else if (gid < PS2) { j = gid - PS1; K = 256; W = W1; Wf = W1f; r768 = j >> 5; kg = j & 31; NTw = 8; }
        else                { j = gid - PS2; K = 256; W = W2; Wf = W2f; r768 = j >> 5; kg = j & 31; NTw = 8; }
        int src = gate_remap(r768);
        const float* s = W + (size_t)src * K + kg * 8;
        f32x4 v0 = *(const f32x4*)s, v1 = *(const f32x4*)(s + 4);
        half8 h;
#pragma unroll
        for (int jj = 0; jj < 4; ++jj) { h[jj] = (_Float16)v0[jj]; h[4 + jj] = (_Float16)v1[jj]; }
        int lane = (r768 & 15) | ((kg & 3) << 4);
        size_t idx = (((size_t)(r768 >> 4) * NTw + (kg >> 2)) * 64 + lane) * 8;
        *(half8*)(Wf + idx) = h;
    } else if (gid < PS4) {
        int j = gid - PS3;
        int l = (j >= 1536) ? 2 : (j >= 768 ? 1 : 0);
        int r = j - l * 768;
        int src = gate_remap(r);
        const float* bi = (l == 0) ? b0i : (l == 1) ? b1i : b2i;
        const float* bh = (l == 0) ? b0h : (l == 1) ? b1h : b2h;
        float* bs       = (l == 0) ? bs0 : (l == 1) ? bs1 : bs2;
        bs[r] = bi[src] + bh[src];
    } else if (gid < PS5) {
        int j = gid - PS4;            // 0..2047: fcW 64 rows x 32 kgroups -> frag-linear
        int r64 = j >> 5, kg = j & 31;
        const float* s = fcW + (size_t)r64 * 256 + kg * 8;
        f32x4 v0 = *(const f32x4*)s, v1 = *(const f32x4*)(s + 4);
        half8 h;
#pragma unroll
        for (int jj = 0; jj < 4; ++jj) { h[jj] = (_Float16)v0[jj]; h[4 + jj] = (_Float16)v1[jj]; }
        int lane = (r64 & 15) | ((kg & 3) << 4);
        size_t idx = (((size_t)(r64 >> 4) * 8 + (kg >> 2)) * 64 + lane) * 8;
        *(half8*)(fWf + idx) = h;
    }
}

// ---------------- mega kernel: 3 layers + fc, one block per 64-row slab ----------------
// 1024 threads = 16 waves; wave w = n-unit nu (0..15). Block b owns rows
// b*64..b*64+63. h1/h2/h3 ping-pong in LDS frag layout:
//   frag (fmLocal, kt) at ((fmLocal*8 + kt)*64 + lane)*8 halfs.
// Per layer per kt: 4 A frags (global xf for L1 / LDS for L2,L3) + 3 W frags
// (global, per-wave nu) + 12 MFMA. Epilogue writes half4v to LDS at
//   ((fm*8 + kt_o)*64 + lane_o)*8 + elem  (verified frag formula, LDS base).

__global__ __launch_bounds__(1024, 4)
void mega_kernel(const _Float16* __restrict__ xf,
                 const _Float16* __restrict__ W0f, const float* __restrict__ bs0,
                 const _Float16* __restrict__ W1f, const float* __restrict__ bs1,
                 const _Float16* __restrict__ W2f, const float* __restrict__ bs2,
                 const _Float16* __restrict__ fWf, const float* __restrict__ fcb,
                 float* __restrict__ out)
{
    __shared__ __align__(16) _Float16 hP[2][64 * 256];   // 32KB each, frag layout

    const int t    = threadIdx.x;
    const int lane = t & 63;
    const int w    = t >> 6;        // wave = nu
    const int lrow = lane & 15;
    const int lkb  = lane >> 4;
    const int b    = blockIdx.x;

    const int kt_o   = w >> 1;
    const int lane_o = lrow | ((((w & 1) << 1) | (lkb >> 1)) << 4);
    const int elem   = (lkb & 1) * 4;
    const int nbase  = w * 16 + lkb * 4;

#define LAYER_EPILOGUE(BS, DST)                                               \
    {                                                                         \
        const f32x4 bI = *(const f32x4*)((BS) + nbase);                       \
        const f32x4 bG = *(const f32x4*)((BS) + 256 + nbase);                 \
        const f32x4 bO = *(const f32x4*)((BS) + 512 + nbase);                 \
        _Pragma("unroll")                                                     \
        for (int fm = 0; fm < 4; ++fm) {                                      \
            half4v oh;                                                        \
            _Pragma("unroll")                                                 \
            for (int j = 0; j < 4; ++j) {                                     \
                float gi = acc[0][fm][j] + bI[j];                             \
                float gg = acc[1][fm][j] + bG[j];                             \
                float go = acc[2][fm][j] + bO[j];                             \
                float c2 = fsig(gi) * ftanh(gg);                              \
                oh[j] = (_Float16)(fsig(go) * ftanh(c2));                     \
            }                                                                 \
            *(half4v*)((DST) + ((fm * 8 + kt_o) * 64 + lane_o) * 8 + elem) = oh; \
        }                                                                     \
    }

#define MFMA12(w0, w1, w2, a0, a1, a2, a3)                                        \
    acc[0][0] = __builtin_amdgcn_mfma_f32_16x16x32_f16(w0, a0, acc[0][0], 0, 0, 0); \
    acc[0][1] = __builtin_amdgcn_mfma_f32_16x16x32_f16(w0, a1, acc[0][1], 0, 0, 0); \
    acc[0][2] = __builtin_amdgcn_mfma_f32_16x16x32_f16(w0, a2, acc[0][2], 0, 0, 0); \
    acc[0][3] = __builtin_amdgcn_mfma_f32_16x16x32_f16(w0, a3, acc[0][3], 0, 0, 0); \
    acc[1][0] = __builtin_amdgcn_mfma_f32_16x16x32_f16(w1, a0, acc[1][0], 0, 0, 0); \
    acc[1][1] = __builtin_amdgcn_mfma_f32_16x16x32_f16(w1, a1, acc[1][1], 0, 0, 0); \
    acc[1][2] = __builtin_amdgcn_mfma_f32_16x16x32_f16(w1, a2, acc[1][2], 0, 0, 0); \
    acc[1][3] = __builtin_amdgcn_mfma_f32_16x16x32_f16(w1, a3, acc[1][3], 0, 0, 0); \
    acc[2][0] = __builtin_amdgcn_mfma_f32_16x16x32_f16(w2, a0, acc[2][0], 0, 0, 0); \
    acc[2][1] = __builtin_amdgcn_mfma_f32_16x16x32_f16(w2, a1, acc[2][1], 0, 0, 0); \
    acc[2][2] = __builtin_amdgcn_mfma_f32_16x16x32_f16(w2, a2, acc[2][2], 0, 0, 0); \
    acc[2][3] = __builtin_amdgcn_mfma_f32_16x16x32_f16(w2, a3, acc[2][3], 0, 0, 0)

    // ---- layer 1: A from global xf (NT=4), W0f, -> hP[0] ----
    {
        const _Float16* pA = xf + ((size_t)(b * 4) * 4) * 512 + lane * 8;
        const _Float16* pW = W0f + ((size_t)w * 4) * 512 + lane * 8;   // frag(g,kt): +(g*64+kt)*512
        f32x4 acc[3][4];
#pragma unroll
        for (int g = 0; g < 3; ++g)
#pragma unroll
            for (int fm = 0; fm < 4; ++fm) acc[g][fm] = (f32x4)0.f;
#pragma unroll
        for (int kt = 0; kt < 4; ++kt) {
            half8 a0 = *(const half8*)(pA + (size_t)(0 * 4 + kt) * 512);
            half8 a1 = *(const half8*)(pA + (size_t)(1 * 4 + kt) * 512);
            half8 a2 = *(const half8*)(pA + (size_t)(2 * 4 + kt) * 512);
            half8 a3 = *(const half8*)(pA + (size_t)(3 * 4 + kt) * 512);
            half8 w0 = *(const half8*)(pW + (size_t)(0 * 64 + kt) * 512);
            half8 w1 = *(const half8*)(pW + (size_t)(1 * 64 + kt) * 512);
            half8 w2 = *(const half8*)(pW + (size_t)(2 * 64 + kt) * 512);
            MFMA12(w0, w1, w2, a0, a1, a2, a3);
        }
        LAYER_EPILOGUE(bs0, hP[0]);
    }
    __syncthreads();

    // ---- layer 2: A from hP[0] (LDS), W1f (NT=8) -> hP[1] ----
    {
        const _Float16* pW = W1f + ((size_t)w * 8) * 512 + lane * 8;   // frag(g,kt): +(g*128+kt)*512
        const _Float16* pL = hP[0] + lane * 8;
        f32x4 acc[3][4];
#pragma unroll
        for (int g = 0; g < 3; ++g)
#pragma unroll
            for (int fm = 0; fm < 4; ++fm) acc[g][fm] = (f32x4)0.f;
#pragma unroll
        for (int kt = 0; kt < 8; ++kt) {
            half8 a0 = *(const half8*)(pL + (0 * 8 + kt) * 512);
            half8 a1 = *(const half8*)(pL + (1 * 8 + kt) * 512);
            half8 a2 = *(const half8*)(pL + (2 * 8 + kt) * 512);
            half8 a3 = *(const half8*)(pL + (3 * 8 + kt) * 512);
            half8 w0 = *(const half8*)(pW + (size_t)(0 * 128 + kt) * 512);
            half8 w1 = *(const half8*)(pW + (size_t)(1 * 128 + kt) * 512);
            half8 w2 = *(const half8*)(pW + (size_t)(2 * 128 + kt) * 512);
            MFMA12(w0, w1, w2, a0, a1, a2, a3);
        }
        LAYER_EPILOGUE(bs1, hP[1]);
    }
    __syncthreads();

    // ---- layer 3: A from hP[1] (LDS), W2f -> hP[0] ----
    {
        const _Float16* pW = W2f + ((size_t)w * 8) * 512 + lane * 8;
        const _Float16* pL = hP[1] + lane * 8;
        f32x4 acc[3][4];
#pragma unroll
        for (int g = 0; g < 3; ++g)
#pragma unroll
            for (int fm = 0; fm < 4; ++fm) acc[g][fm] = (f32x4)0.f;
#pragma unroll
        for (int kt = 0; kt < 8; ++kt) {
            half8 a0 = *(const half8*)(pL + (0 * 8 + kt) * 512);
            half8 a1 = *(const half8*)(pL + (1 * 8 + kt) * 512);
            half8 a2 = *(const half8*)(pL + (2 * 8 + kt) * 512);
            half8 a3 = *(const half8*)(pL + (3 * 8 + kt) * 512);
            half8 w0 = *(const half8*)(pW + (size_t)(0 * 128 + kt) * 512);
            half8 w1 = *(const half8*)(pW + (size_t)(1 * 128 + kt) * 512);
            half8 w2 = *(const half8*)(pW + (size_t)(2 * 128 + kt) * 512);
            MFMA12(w0, w1, w2, a0, a1, a2, a3);
        }
        LAYER_EPILOGUE(bs2, hP[0]);
    }
    __syncthreads();

    // ---- fc + tanh-softmax-normalize: waves 0..3 (wave = 16-row group) ----
    if (w < 4) {
        const _Float16* pFW = fWf + lane * 8;          // frag(nf,kt): +(nf*8+kt)*512
        const _Float16* pL  = hP[0] + lane * 8;        // A frag (fmLocal=w, kt)
        const int ln = lrow;

        f32x4 acc[4];
#pragma unroll
        for (int nf = 0; nf < 4; ++nf) acc[nf] = (f32x4)0.f;
#pragma unroll
        for (int kt = 0; kt < 8; ++kt) {
            half8 ah = *(const half8*)(pL + (w * 8 + kt) * 512);
#pragma unroll
            for (int nf = 0; nf < 4; ++nf) {
                half8 wf = *(const half8*)(pFW + (size_t)(nf * 8 + kt) * 512);
                acc[nf] = __builtin_amdgcn_mfma_f32_16x16x32_f16(ah, wf, acc[nf], 0, 0, 0);
            }
        }

        float fb[4];
#pragma unroll
        for (int nf = 0; nf < 4; ++nf) fb[nf] = fcb[nf * 16 + ln];

        float tt[4][4], aa[4][4];
#pragma unroll
        for (int nf = 0; nf < 4; ++nf)
#pragma unroll
            for (int r = 0; r < 4; ++r) {
                float o = acc[nf][r] + fb[nf];
                tt[nf][r] = ftanh(o);
                aa[nf][r] = fabsf(o);
            }

        float mx[4];
#pragma unroll
        for (int r = 0; r < 4; ++r)
            mx[r] = fmaxf(fmaxf(aa[0][r], aa[1][r]), fmaxf(aa[2][r], aa[3][r]));
#pragma unroll
        for (int ofs = 1; ofs < 16; ofs <<= 1)
#pragma unroll
            for (int r = 0; r < 4; ++r) mx[r] = fmaxf(mx[r], __shfl_xor(mx[r], ofs, 64));

        float ee[4][4], Z[4];
#pragma unroll
        for (int r = 0; r < 4; ++r) Z[r] = 0.f;
#pragma unroll
        for (int nf = 0; nf < 4; ++nf)
#pragma unroll
            for (int r = 0; r < 4; ++r) { ee[nf][r] = __expf(aa[nf][r] - mx[r]); Z[r] += ee[nf][r]; }
#pragma unroll
        for (int ofs = 1; ofs < 16; ofs <<= 1)
#pragma unroll
            for (int r = 0; r < 4; ++r) Z[r] += __shfl_xor(Z[r], ofs, 64);

        float wv[4][4], S[4];
#pragma unroll
        for (int r = 0; r < 4; ++r) S[r] = 0.f;
#pragma unroll
        for (int r = 0; r < 4; ++r) {
            const float rz = frcp(Z[r]);
#pragma unroll
            for (int nf = 0; nf < 4; ++nf) { wv[nf][r] = tt[nf][r] * ee[nf][r] * rz; S[r] += fabsf(wv[nf][r]); }
        }
#pragma unroll
        for (int ofs = 1; ofs < 16; ofs <<= 1)
#pragma unroll
            for (int r = 0; r < 4; ++r) S[r] += __shfl_xor(S[r], ofs, 64);

#pragma unroll
        for (int r = 0; r < 4; ++r) {
            const float inv = frcp(fmaxf(S[r], 1e-12f));
            const int m = b * 64 + w * 16 + lkb * 4 + r;
#pragma unroll
            for (int nf = 0; nf < 4; ++nf)
                out[(size_t)m * 64 + nf * 16 + ln] = wv[nf][r] * inv;
        }
    }
#undef LAYER_EPILOGUE
#undef MFMA12
}

// ---------------- launch ----------------

extern "C" void kernel_launch(void* const* d_in, const int* in_sizes, int n_in,
                              void* d_out, int out_size, void* d_ws, size_t ws_size,
                              hipStream_t stream) {
    const float* x    = (const float*)d_in[0];
    const float* Wih0 = (const float*)d_in[1];
    const float* bih0 = (const float*)d_in[3];
    const float* bhh0 = (const float*)d_in[4];
    const float* Wih1 = (const float*)d_in[5];
    const float* bih1 = (const float*)d_in[7];
    const float* bhh1 = (const float*)d_in[8];
    const float* Wih2 = (const float*)d_in[9];
    const float* bih2 = (const float*)d_in[11];
    const float* bhh2 = (const float*)d_in[12];
    const float* fcW  = (const float*)d_in[13];
    const float* fcb  = (const float*)d_in[14];

    char* ws = (char*)d_ws;
    _Float16* xf  = (_Float16*)(ws);                   // 4 MB frag-linear
    _Float16* W0f = (_Float16*)(ws + (4u << 20));      // 192 KB
    _Float16* W1f = (_Float16*)(ws + (5u << 20));      // 384 KB
    _Float16* W2f = (_Float16*)(ws + (6u << 20));      // 384 KB
    _Float16* fWf = (_Float16*)(ws + (7u << 20));      // 32 KB frag-linear
    float*    bs0 = (float*)(ws + (8u << 20));
    float*    bs1 = (float*)(ws + (8u << 20) + 4096);
    float*    bs2 = (float*)(ws + (8u << 20) + 8192);
    float*    outp = (float*)d_out;

    prep_all_kernel<<<dim3((PS5 + 255) / 256), dim3(256), 0, stream>>>(
        x, Wih0, bih0, bhh0, Wih1, bih1, bhh1, Wih2, bih2, bhh2, fcW,
        xf, W0f, W1f, W2f, bs0, bs1, bs2, fWf);

    mega_kernel<<<dim3(NROWS / 64), dim3(1024), 0, stream>>>(
        xf, W0f, bs0, W1f, bs1, W2f, bs2, fWf, fcb, outp);
}